// Round 8
// baseline (718.995 us; speedup 1.0000x reference)
//
#include <hip/hip_runtime.h>
#include <hip/hip_bf16.h>
#include <math.h>

#define M_BATCH   4096
#define K_IN      4096
#define N_OUT     4096
#define NELEM     16777216   // 4096*4096

typedef __bf16 bf16;
typedef bf16  bf16x8 __attribute__((ext_vector_type(8)));
typedef float f32x4  __attribute__((ext_vector_type(4)));
typedef float f32x16 __attribute__((ext_vector_type(16)));
typedef unsigned short u16;
typedef u16 u16x8 __attribute__((ext_vector_type(8)));

// fast softplus: hardware v_exp/v_log, poly for small e (w_sigma in [-12,-2.2])
__device__ __forceinline__ float softplus_fast(float x) {
    if (x > 15.f) return x;
    const float e = __expf(x);
    if (e < 0.0883f)  // log1p(e) = e - e^2/2 + e^3/3, trunc err < 2e-6 rel
        return e * (1.f + e * (-0.5f + e * 0.3333333f));
    return __logf(1.f + e);
}

__device__ __forceinline__ unsigned short f2bf_bits(float x) {
    bf16 b = (bf16)x;
    return __builtin_bit_cast(unsigned short, b);
}

// async global->LDS, 16B per lane. LDS dst must be wave-uniform base + lane*16.
__device__ __forceinline__ void gload_lds16(const void* g, void* l) {
    __builtin_amdgcn_global_load_lds(
        (__attribute__((address_space(1))) void*)g,
        (__attribute__((address_space(3))) void*)l,
        16, 0, 0);
}

// ---------------------------------------------------------------------------
// prep_all v2 (R6, kept unchanged this round for clean attribution).
// ---------------------------------------------------------------------------
__global__ __launch_bounds__(256) void prep_all(const float* __restrict__ wmu,
                                                const float* __restrict__ wsg,
                                                bf16* __restrict__ Wmu_t,
                                                bf16* __restrict__ Wsg_t,
                                                float* __restrict__ partials,
                                                const float4* __restrict__ mu,
                                                u16x8* __restrict__ A8,
                                                u16x8* __restrict__ A28) {
    __shared__ bf16 tmu[128][65];
    __shared__ bf16 tsg[128][65];
    __shared__ float wred[4][3];

    const int t   = threadIdx.x;
    const int bid = blockIdx.x;

    if (bid >= 2048) {                       // ---- prep_a part ----
        const int i = (bid - 2048) * 256 + t;        // u16x8-granule index
        const float4 v0 = mu[2 * i];
        const float4 v1 = mu[2 * i + 1];
        u16x8 a, a2;
        a[0] = f2bf_bits(v0.x); a[1] = f2bf_bits(v0.y);
        a[2] = f2bf_bits(v0.z); a[3] = f2bf_bits(v0.w);
        a[4] = f2bf_bits(v1.x); a[5] = f2bf_bits(v1.y);
        a[6] = f2bf_bits(v1.z); a[7] = f2bf_bits(v1.w);
        a2[0] = f2bf_bits(v0.x * v0.x); a2[1] = f2bf_bits(v0.y * v0.y);
        a2[2] = f2bf_bits(v0.z * v0.z); a2[3] = f2bf_bits(v0.w * v0.w);
        a2[4] = f2bf_bits(v1.x * v1.x); a2[5] = f2bf_bits(v1.y * v1.y);
        a2[6] = f2bf_bits(v1.z * v1.z); a2[7] = f2bf_bits(v1.w * v1.w);
        A8[i]  = a;
        A28[i] = a2;
        return;
    }

    // ---- prep_w part: 128(i) x 64(o) tile ----
    const int ti = bid >> 6;            // i (K) tile, 0..31  (128 rows each)
    const int tj = bid & 63;            // o (N) tile, 0..63  (64 cols each)
    const int r  = t >> 4;              // 0..15
    const int c4 = (t & 15) << 2;       // 0,4,..,60

    float s_abs = 0.f, s_sp = 0.f, s_log = 0.f;

    for (int rr = 0; rr < 128; rr += 16) {
        const int row = rr + r;
        const size_t goff = (size_t)(ti * 128 + row) * N_OUT + tj * 64 + c4;
        const float4 vm = *(const float4*)(wmu + goff);
        const float4 vs = *(const float4*)(wsg + goff);
        const float sp0 = softplus_fast(vs.x), sp1 = softplus_fast(vs.y);
        const float sp2 = softplus_fast(vs.z), sp3 = softplus_fast(vs.w);
        s_abs += fabsf(vm.x) + fabsf(vm.y) + fabsf(vm.z) + fabsf(vm.w);
        s_sp  += sp0 + sp1 + sp2 + sp3;
        s_log += __logf(sp0) + __logf(sp1) + __logf(sp2) + __logf(sp3);
        tmu[row][c4 + 0] = (bf16)vm.x; tmu[row][c4 + 1] = (bf16)vm.y;
        tmu[row][c4 + 2] = (bf16)vm.z; tmu[row][c4 + 3] = (bf16)vm.w;
        tsg[row][c4 + 0] = (bf16)sp0;  tsg[row][c4 + 1] = (bf16)sp1;
        tsg[row][c4 + 2] = (bf16)sp2;  tsg[row][c4 + 3] = (bf16)sp3;
    }
    __syncthreads();

    // transposed write: Wt[o][i] = tile[i][o]; 16 threads x 16 B = 256 B/row
#pragma unroll
    for (int p = 0; p < 4; ++p) {
        const int jj = p * 16 + (t >> 4);   // o within tile
        const int i0 = (t & 15) << 3;       // i chunk (8 elems)
        u16x8 om, os;
#pragma unroll
        for (int e = 0; e < 8; ++e) {
            om[e] = __builtin_bit_cast(unsigned short, tmu[i0 + e][jj]);
            os[e] = __builtin_bit_cast(unsigned short, tsg[i0 + e][jj]);
        }
        const size_t o = (size_t)(tj * 64 + jj) * K_IN + ti * 128 + i0;
        *(u16x8*)(Wmu_t + o) = om;
        *(u16x8*)(Wsg_t + o) = os;
    }

    // KL partials: shfl_xor wave-reduce, one LDS combine
    float v0 = s_log, v1 = s_sp, v2 = s_abs;
#pragma unroll
    for (int off = 32; off; off >>= 1) {
        v0 += __shfl_xor(v0, off, 64);
        v1 += __shfl_xor(v1, off, 64);
        v2 += __shfl_xor(v2, off, 64);
    }
    if ((t & 63) == 0) {
        wred[t >> 6][0] = v0; wred[t >> 6][1] = v1; wred[t >> 6][2] = v2;
    }
    __syncthreads();
    if (t == 0) {
        partials[0 * 2048 + bid] = wred[0][0] + wred[1][0] + wred[2][0] + wred[3][0];
        partials[1 * 2048 + bid] = wred[0][1] + wred[1][1] + wred[2][1] + wred[3][1];
        partials[2 * 2048 + bid] = wred[0][2] + wred[1][2] + wred[2][2] + wred[3][2];
    }
}

// ---------------------------------------------------------------------------
// gemm_bf16: C[M,N] = A[M,K](bf16) * Bt[N,K]^T(bf16) + bias  (fp32 out)
// R8: OCCUPANCY 2 -> 4 waves/SIMD. Same 256x256 tile / BK=64 / 128 KiB dbuf
// LDS / R6 flat layout ([par][256][64], 16B-chunk XOR swizzle) / 32x32x16
// MFMA / R4 4-barrier skeleton — but 16 waves of 1024 threads (4M x 4N,
// 64x64 out per wave, acc = 2x2 f32x16 = 64 VGPR). __launch_bounds__(1024,4)
// caps VGPR at 128 so the full block is co-resident at 4 waves/SIMD,
// doubling the TLP available to hide the ~450 cyc/phase of sync+LDS latency
// that 2 waves/SIMD could not (R2/R3/R4/R7 all <=4%).
// Scaled ledger (1 gload per STAGE): prologue 8 loads, vmcnt(4); loop
// vmcnt(2)@ph4 retires {A,B}(kt+1); vmcnt(2)@ph8 retires {A,B}(kt+2).
// B bulk-read at q0 (pair0+pair1); end-ph2/ph6 barriers protect the B
// restage (same WAR proof as R0). Per-acc k-order ks0..3 unchanged ->
// bitwise-identical C. XCD 4x8 remap kept (FETCH -33%, R2-confirmed).
// Phase q: m = q&1, pair = q>>1; A-frags 2x b128; 4 MFMA.
// ---------------------------------------------------------------------------
#define MFMA32 __builtin_amdgcn_mfma_f32_32x32x16_bf16

__global__ __launch_bounds__(1024, 4) void gemm_bf16(
    const bf16* __restrict__ A1,  const bf16* __restrict__ Bt1,
    const float* __restrict__ bias1, float* __restrict__ C1,
    const bf16* __restrict__ A2_, const bf16* __restrict__ Bt2,
    const float* __restrict__ bias2, float* __restrict__ C2) {

    __shared__ bf16 As[2 * 256 * 64];   // [par][row 256][k 64], 64 KiB
    __shared__ bf16 Bs[2 * 256 * 64];   // 64 KiB

    const int z = blockIdx.z;
    const bf16*  A    = z ? A2_   : A1;
    const bf16*  Bt   = z ? Bt2   : Bt1;
    const float* bias = z ? bias2 : bias1;
    float*       C    = z ? C2    : C1;

    const int t = threadIdx.x;
    // XCD-aware remap: each XCD gets a contiguous 4x8 block of the tile grid.
    const int id   = blockIdx.y * 16 + blockIdx.x;  // 0..255 per z-slice
    const int xcd  = id & 7, cc_ = id >> 3;
    const int rowBase = (((xcd >> 1) << 2) + (cc_ >> 3)) << 8;
    const int colBase = (((xcd & 1) << 3) + (cc_ & 7)) << 8;

    // ---- staging: 1024 threads x 16 B = 16 KB = one 128-row half-tile.
    // gload_lds writes linear (t*16); source chunk inverse-swizzled (rule 21).
    const int srow   = t >> 3;                  // 0..127
    const int schunk = (t & 7) ^ (srow & 7);    // source 16B chunk within row
    const char* aG = (const char*)(A  + (size_t)(rowBase + srow) * K_IN + schunk * 8);
    const char* bG = (const char*)(Bt + (size_t)(colBase + srow) * K_IN + schunk * 8);
    char* aL = (char*)As + t * 16;
    char* bL = (char*)Bs + t * 16;

#define STAGE_A(kt, h, par)                                                    \
    gload_lds16(aG + ((size_t)((kt) & 63) << 7) + (size_t)(h) * (128 * K_IN * 2), \
                aL + ((par) << 15) + ((h) << 14))
#define STAGE_B(kt, h, par)                                                    \
    gload_lds16(bG + ((size_t)((kt) & 63) << 7) + (size_t)(h) * (128 * K_IN * 2), \
                bL + ((par) << 15) + ((h) << 14))

    // ---- fragment read addressing (32x32x16, flat 128B rows) ----
    const int lane = t & 63;
    const int wave = t >> 6;             // 0..15
    const int wr = wave >> 2;            // 0..3 : M quarter (64 rows)
    const int wc = wave & 3;             // 0..3 : N quarter (64 cols)
    const int fr = lane & 31;            // row within 32-row frag
    const int kh = lane >> 5;            // k-half (8 of 16 k per slice)
    int cS[4];                           // swizzled 16B-chunk byte offsets
#pragma unroll
    for (int s = 0; s < 4; ++s)
        cS[s] = (((s << 1) | kh) ^ (fr & 7)) << 4;
    const char* aRd = (const char*)As + ((wr << 6) + fr) * 128;
    const char* bRd = (const char*)Bs + ((wc << 6) + fr) * 128;

#define DS_A(par, m, ks) (*(const bf16x8*)(aRd + ((par) << 15) + ((m) << 12) + cS[ks]))
#define DS_B(par, n, ks) (*(const bf16x8*)(bRd + ((par) << 15) + ((n) << 12) + cS[ks]))

// Phase q: m = q&1, pair = q>>1. q0 bulk-reads all B (both pairs).
// BAR: 0 = free-run, 1 = barrier after MFMA; VM: vmcnt(2) before barrier.
#define PHASE(par, q, STAGE_STMT, VM, BAR) do {                                \
        if ((q) == 0) {                                                        \
            _Pragma("unroll")                                                  \
            for (int pp = 0; pp < 2; ++pp)                                     \
                _Pragma("unroll")                                              \
                for (int n = 0; n < 2; ++n)                                    \
                    _Pragma("unroll")                                          \
                    for (int j = 0; j < 2; ++j)                                \
                        bfrag[pp][n][j] = DS_B(par, n, pp * 2 + j);            \
        }                                                                      \
        bf16x8 a_[2];                                                          \
        _Pragma("unroll")                                                      \
        for (int j = 0; j < 2; ++j)                                            \
            a_[j] = DS_A(par, (q) & 1, ((q) >> 1) * 2 + j);                    \
        STAGE_STMT;                                                            \
        __builtin_amdgcn_s_setprio(1);                                         \
        _Pragma("unroll")                                                      \
        for (int j = 0; j < 2; ++j) {                                          \
            acc[(q) & 1][0] = MFMA32(a_[j], bfrag[(q) >> 1][0][j],             \
                                     acc[(q) & 1][0], 0, 0, 0);                \
            acc[(q) & 1][1] = MFMA32(a_[j], bfrag[(q) >> 1][1][j],             \
                                     acc[(q) & 1][1], 0, 0, 0);                \
        }                                                                      \
        __builtin_amdgcn_s_setprio(0);                                         \
        if (VM) {                                                              \
            asm volatile("s_waitcnt vmcnt(2)" ::: "memory");                   \
            __builtin_amdgcn_sched_barrier(0);                                 \
        }                                                                      \
        if (BAR) {                                                             \
            __builtin_amdgcn_sched_barrier(0);                                 \
            __builtin_amdgcn_s_barrier();                                      \
            __builtin_amdgcn_sched_barrier(0);                                 \
        }                                                                      \
    } while (0)

    f32x16 acc[2][2];
#pragma unroll
    for (int m = 0; m < 2; ++m)
#pragma unroll
        for (int n = 0; n < 2; ++n)
#pragma unroll
            for (int e = 0; e < 16; ++e) acc[m][n][e] = 0.f;

    bf16x8 bfrag[2][2][2];   // [pair][n][j]

    // prologue: stage kt0 + kt1 fully (8 loads); retire kt0 (keep kt1 in flight)
    STAGE_A(0, 0, 0); STAGE_A(0, 1, 0);
    STAGE_B(0, 0, 0); STAGE_B(0, 1, 0);
    STAGE_A(1, 0, 1); STAGE_A(1, 1, 1);
    STAGE_B(1, 0, 1); STAGE_B(1, 1, 1);
    asm volatile("s_waitcnt vmcnt(4)" ::: "memory");
    __builtin_amdgcn_sched_barrier(0);
    __builtin_amdgcn_s_barrier();
    __builtin_amdgcn_sched_barrier(0);

    for (int i = 0; i < 32; ++i) {          // 2 K-tiles per iter, K = 64*64
        const int kA1 = 2 * i + 1;          // A(kt+1) -> par1 (restage noop i=0)
        const int kB0 = 2 * i + 2;          // B(kt+2) -> par0
        const int kA0 = 2 * i + 2;          // A(kt+2) -> par0
        const int kB1 = 2 * i + 3;          // B(kt+3) -> par1
        // phases 1-4: compute kt=2i from par0
        PHASE(0, 0, STAGE_A(kA1, 0, 1), 0, 0);
        PHASE(0, 1, STAGE_A(kA1, 1, 1), 0, 1);   // end-ph2 barrier
        PHASE(0, 2, STAGE_B(kB0, 0, 0), 0, 0);
        PHASE(0, 3, STAGE_B(kB0, 1, 0), 1, 1);   // vmcnt(2) + end-ph4 barrier
        // phases 5-8: compute kt=2i+1 from par1
        PHASE(1, 0, STAGE_A(kA0, 0, 0), 0, 0);
        PHASE(1, 1, STAGE_A(kA0, 1, 0), 0, 1);   // end-ph6 barrier
        PHASE(1, 2, STAGE_B(kB1, 0, 1), 0, 0);
        PHASE(1, 3, STAGE_B(kB1, 1, 1), 1, 1);   // vmcnt(2) + end-ph8 barrier
    }

    asm volatile("s_waitcnt vmcnt(0)" ::: "memory");  // drain tail junk loads

    // epilogue: 32x32 C/D layout col=lane&31, row=(reg&3)+8*(reg>>2)+4*kh
#pragma unroll
    for (int n = 0; n < 2; ++n) {
        const int c = colBase + (wc << 6) + (n << 5) + fr;
        float b = bias[c];
        if (z) b = softplus_fast(b);
#pragma unroll
        for (int m = 0; m < 2; ++m) {
            const int rb = rowBase + (wr << 6) + (m << 5) + (kh << 2);
#pragma unroll
            for (int reg = 0; reg < 16; ++reg) {
                const int row = rb + (reg & 3) + ((reg >> 2) << 3);
                C[(size_t)row * N_OUT + c] = acc[m][n][reg] + b;
            }
        }
    }
#undef STAGE_A
#undef STAGE_B
#undef DS_A
#undef DS_B
#undef PHASE
}

// ---------------------------------------------------------------------------
// kl_finish: reduce partials (3 x n) in double, write scalar kl.
// ---------------------------------------------------------------------------
__global__ __launch_bounds__(256) void kl_finish(const float* __restrict__ partials,
                                                 const int n,
                                                 float* __restrict__ out) {
    __shared__ double red[256];
    const int t = threadIdx.x;
    double sums[3];
    for (int v = 0; v < 3; v++) {
        double a = 0.0;
        for (int i = t; i < n; i += 256) a += (double)partials[v * n + i];
        red[t] = a;
        __syncthreads();
        for (int s = 128; s > 0; s >>= 1) {
            if (t < s) red[t] += red[t + s];
            __syncthreads();
        }
        sums[v] = red[0];
        __syncthreads();
    }
    if (t == 0) {
        const double mean_log = sums[0] / 16777216.0;
        const double mean_sp  = sums[1] / 16777216.0;
        const double kl = -0.5 * (4096.0 * mean_log - sums[2] - 4096.0 * mean_sp);
        out[0] = (float)kl;
    }
}

// ---------------------------------------------------------------------------
// Fallback (only if ws too small): naive fp32 dual GEMM + partials.
// ---------------------------------------------------------------------------
__global__ void fb_partials(const float* __restrict__ wmu,
                            const float* __restrict__ wsg,
                            float* __restrict__ partials) {
    __shared__ float red[256];
    const int t = threadIdx.x;
    float s_abs = 0.f, s_sp = 0.f, s_log = 0.f;
    for (int i = blockIdx.x * 256 + t; i < NELEM; i += 1024 * 256) {
        s_abs += fabsf(wmu[i]);
        const float sp = softplus_fast(wsg[i]);
        s_sp += sp;
        s_log += __logf(sp);
    }
    float vals[3] = { s_log, s_sp, s_abs };
    for (int v = 0; v < 3; v++) {
        __syncthreads();
        red[t] = vals[v];
        __syncthreads();
        for (int s = 128; s > 0; s >>= 1) {
            if (t < s) red[t] += red[t + s];
            __syncthreads();
        }
        if (t == 0) partials[v * 1024 + blockIdx.x] = red[0];
    }
}

__global__ void fb_gemm(const float* __restrict__ A,
                        const float* __restrict__ Wm,
                        const float* __restrict__ Ws,
                        const float* __restrict__ bmu,
                        const float* __restrict__ bsg,
                        float* __restrict__ Cmu,
                        float* __restrict__ Csg) {
    __shared__ float As_[16][17], Bm[16][17], Bs_[16][17];
    const int tx = threadIdx.x, ty = threadIdx.y;
    const int row = blockIdx.y * 16 + ty;
    const int col = blockIdx.x * 16 + tx;
    float am = 0.f, as = 0.f;
    for (int k0 = 0; k0 < K_IN; k0 += 16) {
        As_[ty][tx] = A[(size_t)row * K_IN + k0 + tx];
        Bm[ty][tx]  = Wm[(size_t)(k0 + ty) * N_OUT + col];
        Bs_[ty][tx] = softplus_fast(Ws[(size_t)(k0 + ty) * N_OUT + col]);
        __syncthreads();
#pragma unroll
        for (int kk = 0; kk < 16; kk++) {
            const float av = As_[ty][kk];
            am += av * Bm[kk][tx];
            as += av * av * Bs_[kk][tx];
        }
        __syncthreads();
    }
    Cmu[(size_t)row * N_OUT + col] = am + bmu[col];
    Csg[(size_t)row * N_OUT + col] = as + softplus_fast(bsg[col]);
}

// ---------------------------------------------------------------------------
extern "C" void kernel_launch(void* const* d_in, const int* in_sizes, int n_in,
                              void* d_out, int out_size, void* d_ws, size_t ws_size,
                              hipStream_t stream) {
    const float* mu_in   = (const float*)d_in[0];
    // d_in[1] (sigma_in) unused by the reference
    const float* w_mu    = (const float*)d_in[2];
    const float* w_sigma = (const float*)d_in[3];
    const float* b_mu    = (const float*)d_in[4];
    const float* b_sigma = (const float*)d_in[5];

    float* out_mu  = (float*)d_out;
    float* out_sig = out_mu + (size_t)NELEM;
    float* out_kl  = out_mu + 2 * (size_t)NELEM;

    const size_t mat  = (size_t)NELEM;
    const size_t need = mat * 2 * 4 /* 4 bf16 matrices */ + 3 * 4096 * sizeof(float);

    if (ws_size >= need) {
        bf16* A      = (bf16*)d_ws;
        bf16* A2     = A + mat;
        bf16* Wmu_t  = A2 + mat;
        bf16* Wsg_t  = Wmu_t + mat;
        float* parts = (float*)(Wsg_t + mat);

        prep_all<<<2048 + 8192, 256, 0, stream>>>(
            w_mu, w_sigma, Wmu_t, Wsg_t, parts,
            (const float4*)mu_in, (u16x8*)A, (u16x8*)A2);
        gemm_bf16<<<dim3(16, 16, 2), 1024, 0, stream>>>(
            A, Wmu_t, b_mu, out_mu, A2, Wsg_t, b_sigma, out_sig);
        kl_finish<<<1, 256, 0, stream>>>(parts, 2048, out_kl);
    } else {
        // emergency fallback: slow but correct fp32 path (needs 12KB ws)
        float* parts = (float*)d_ws;
        fb_partials<<<1024, 256, 0, stream>>>(w_mu, w_sigma, parts);
        fb_gemm<<<dim3(256, 256), dim3(16, 16), 0, stream>>>(
            mu_in, w_mu, w_sigma, b_mu, b_sigma, out_mu, out_sig);
        kl_finish<<<1, 256, 0, stream>>>(parts, 1024, out_kl);
    }
}

// Round 9
// 645.949 us; speedup vs baseline: 1.1131x; 1.1131x over previous
//
#include <hip/hip_runtime.h>
#include <hip/hip_bf16.h>
#include <math.h>

#define M_BATCH   4096
#define K_IN      4096
#define N_OUT     4096
#define NELEM     16777216   // 4096*4096

typedef __bf16 bf16;
typedef bf16  bf16x8 __attribute__((ext_vector_type(8)));
typedef float f32x4  __attribute__((ext_vector_type(4)));
typedef float f32x16 __attribute__((ext_vector_type(16)));
typedef unsigned short u16;
typedef u16 u16x8 __attribute__((ext_vector_type(8)));

// fast softplus: hardware v_exp/v_log, poly for small e (w_sigma in [-12,-2.2])
__device__ __forceinline__ float softplus_fast(float x) {
    if (x > 15.f) return x;
    const float e = __expf(x);
    if (e < 0.0883f)  // log1p(e) = e - e^2/2 + e^3/3, trunc err < 2e-6 rel
        return e * (1.f + e * (-0.5f + e * 0.3333333f));
    return __logf(1.f + e);
}

__device__ __forceinline__ unsigned short f2bf_bits(float x) {
    bf16 b = (bf16)x;
    return __builtin_bit_cast(unsigned short, b);
}

// async global->LDS, 16B per lane. LDS dst must be wave-uniform base + lane*16.
__device__ __forceinline__ void gload_lds16(const void* g, void* l) {
    __builtin_amdgcn_global_load_lds(
        (__attribute__((address_space(1))) void*)g,
        (__attribute__((address_space(3))) void*)l,
        16, 0, 0);
}

// ---------------------------------------------------------------------------
// prep_all v2 (R6, kept unchanged).
// ---------------------------------------------------------------------------
__global__ __launch_bounds__(256) void prep_all(const float* __restrict__ wmu,
                                                const float* __restrict__ wsg,
                                                bf16* __restrict__ Wmu_t,
                                                bf16* __restrict__ Wsg_t,
                                                float* __restrict__ partials,
                                                const float4* __restrict__ mu,
                                                u16x8* __restrict__ A8,
                                                u16x8* __restrict__ A28) {
    __shared__ bf16 tmu[128][65];
    __shared__ bf16 tsg[128][65];
    __shared__ float wred[4][3];

    const int t   = threadIdx.x;
    const int bid = blockIdx.x;

    if (bid >= 2048) {                       // ---- prep_a part ----
        const int i = (bid - 2048) * 256 + t;        // u16x8-granule index
        const float4 v0 = mu[2 * i];
        const float4 v1 = mu[2 * i + 1];
        u16x8 a, a2;
        a[0] = f2bf_bits(v0.x); a[1] = f2bf_bits(v0.y);
        a[2] = f2bf_bits(v0.z); a[3] = f2bf_bits(v0.w);
        a[4] = f2bf_bits(v1.x); a[5] = f2bf_bits(v1.y);
        a[6] = f2bf_bits(v1.z); a[7] = f2bf_bits(v1.w);
        a2[0] = f2bf_bits(v0.x * v0.x); a2[1] = f2bf_bits(v0.y * v0.y);
        a2[2] = f2bf_bits(v0.z * v0.z); a2[3] = f2bf_bits(v0.w * v0.w);
        a2[4] = f2bf_bits(v1.x * v1.x); a2[5] = f2bf_bits(v1.y * v1.y);
        a2[6] = f2bf_bits(v1.z * v1.z); a2[7] = f2bf_bits(v1.w * v1.w);
        A8[i]  = a;
        A28[i] = a2;
        return;
    }

    // ---- prep_w part: 128(i) x 64(o) tile ----
    const int ti = bid >> 6;            // i (K) tile, 0..31  (128 rows each)
    const int tj = bid & 63;            // o (N) tile, 0..63  (64 cols each)
    const int r  = t >> 4;              // 0..15
    const int c4 = (t & 15) << 2;       // 0,4,..,60

    float s_abs = 0.f, s_sp = 0.f, s_log = 0.f;

    for (int rr = 0; rr < 128; rr += 16) {
        const int row = rr + r;
        const size_t goff = (size_t)(ti * 128 + row) * N_OUT + tj * 64 + c4;
        const float4 vm = *(const float4*)(wmu + goff);
        const float4 vs = *(const float4*)(wsg + goff);
        const float sp0 = softplus_fast(vs.x), sp1 = softplus_fast(vs.y);
        const float sp2 = softplus_fast(vs.z), sp3 = softplus_fast(vs.w);
        s_abs += fabsf(vm.x) + fabsf(vm.y) + fabsf(vm.z) + fabsf(vm.w);
        s_sp  += sp0 + sp1 + sp2 + sp3;
        s_log += __logf(sp0) + __logf(sp1) + __logf(sp2) + __logf(sp3);
        tmu[row][c4 + 0] = (bf16)vm.x; tmu[row][c4 + 1] = (bf16)vm.y;
        tmu[row][c4 + 2] = (bf16)vm.z; tmu[row][c4 + 3] = (bf16)vm.w;
        tsg[row][c4 + 0] = (bf16)sp0;  tsg[row][c4 + 1] = (bf16)sp1;
        tsg[row][c4 + 2] = (bf16)sp2;  tsg[row][c4 + 3] = (bf16)sp3;
    }
    __syncthreads();

    // transposed write: Wt[o][i] = tile[i][o]; 16 threads x 16 B = 256 B/row
#pragma unroll
    for (int p = 0; p < 4; ++p) {
        const int jj = p * 16 + (t >> 4);   // o within tile
        const int i0 = (t & 15) << 3;       // i chunk (8 elems)
        u16x8 om, os;
#pragma unroll
        for (int e = 0; e < 8; ++e) {
            om[e] = __builtin_bit_cast(unsigned short, tmu[i0 + e][jj]);
            os[e] = __builtin_bit_cast(unsigned short, tsg[i0 + e][jj]);
        }
        const size_t o = (size_t)(tj * 64 + jj) * K_IN + ti * 128 + i0;
        *(u16x8*)(Wmu_t + o) = om;
        *(u16x8*)(Wsg_t + o) = os;
    }

    // KL partials: shfl_xor wave-reduce, one LDS combine
    float v0 = s_log, v1 = s_sp, v2 = s_abs;
#pragma unroll
    for (int off = 32; off; off >>= 1) {
        v0 += __shfl_xor(v0, off, 64);
        v1 += __shfl_xor(v1, off, 64);
        v2 += __shfl_xor(v2, off, 64);
    }
    if ((t & 63) == 0) {
        wred[t >> 6][0] = v0; wred[t >> 6][1] = v1; wred[t >> 6][2] = v2;
    }
    __syncthreads();
    if (t == 0) {
        partials[0 * 2048 + bid] = wred[0][0] + wred[1][0] + wred[2][0] + wred[3][0];
        partials[1 * 2048 + bid] = wred[0][1] + wred[1][1] + wred[2][1] + wred[3][1];
        partials[2 * 2048 + bid] = wred[0][2] + wred[1][2] + wred[2][2] + wred[3][2];
    }
}

// ---------------------------------------------------------------------------
// gemm_bf16: C[M,N] = A[M,K](bf16) * Bt[N,K]^T(bf16) + bias  (fp32 out)
// R9: B IN REGISTERS (LDS traffic cut). R8 proved the kernel LDS-pipe-bound
// (4-wave/SIMD raised LDS traffic 33% -> 436us). Back to 8 waves (2M x 4N,
// 128x64/wave, acc 128 VGPR, 2 waves/SIMD). A stays LDS-staged (R6 flat
// [par][256][64], 16B-chunk XOR swizzle, gload_lds). B is loaded straight
// from global into per-wave registers (L2-hot: per-XCD K-tile window ~256KB
// << 4MiB; same 16B/lane request granularity as before -> FETCH flat).
// Effects: LDS/phase 64KB -> 40KB; B-restage WAR barriers (end-ph2/ph6)
// gone -> 2 barriers/iter; gload stream halved.
// Mixed-stream vmcnt ledger (in-order counter; issue order pinned by
// sched_barrier(0) before each B-block so A-gloads cannot cross):
//   per iter: ph1/2 A(kt+1)->par1 (4 gloads); ph4-post B(kt+2)->b0 (8);
//             ph5/6 A(kt+2)->par0 (4); ph8-post B(kt+3)->b1 (8).
//   vmcnt(8)@ph4 retires {b1_prev 8, A 4} (keeps new b0 in flight);
//   vmcnt(8)@ph8 retires {b0 8, A 4} (keeps new b1). Compiler additionally
//   auto-waits B register uses (can only over-wait, never under).
// Tail B-loads wrap &63 (junk) and are kept live via asm so DCE cannot
// shift the vmcnt counts (rule 17). MFMA per-acc order unchanged from R6
// -> bitwise-identical C. XCD 4x8 remap kept (FETCH -33%, R2-confirmed).
// ---------------------------------------------------------------------------
#define MFMA32 __builtin_amdgcn_mfma_f32_32x32x16_bf16

__global__ __launch_bounds__(512, 2) void gemm_bf16(
    const bf16* __restrict__ A1,  const bf16* __restrict__ Bt1,
    const float* __restrict__ bias1, float* __restrict__ C1,
    const bf16* __restrict__ A2_, const bf16* __restrict__ Bt2,
    const float* __restrict__ bias2, float* __restrict__ C2) {

    __shared__ bf16 As[2 * 256 * 64];   // [par][row 256][k 64], 64 KiB total

    const int z = blockIdx.z;
    const bf16*  A    = z ? A2_   : A1;
    const bf16*  Bt   = z ? Bt2   : Bt1;
    const float* bias = z ? bias2 : bias1;
    float*       C    = z ? C2    : C1;

    const int t = threadIdx.x;
    // XCD-aware remap: each XCD gets a contiguous 4x8 block of the tile grid.
    const int id   = blockIdx.y * 16 + blockIdx.x;  // 0..255 per z-slice
    const int xcd  = id & 7, cc_ = id >> 3;
    const int rowBase = (((xcd >> 1) << 2) + (cc_ >> 3)) << 8;
    const int colBase = (((xcd & 1) << 3) + (cc_ & 7)) << 8;

    // ---- A staging (R6): gload_lds writes linear (t*16); source chunk
    // inverse-swizzled so reads can swizzle (rule 21).
    const int srow   = t >> 3;                  // 0..63 (row within 64-row slab)
    const int schunk = (t & 7) ^ (srow & 7);    // source 16B chunk within row
    const char* aG = (const char*)(A + (size_t)(rowBase + srow) * K_IN + schunk * 8);
    char* aL = (char*)As + t * 16;

#define STAGE_A(kt, h, par) do {                                               \
        const size_t kb_ = (size_t)((kt) & 63) << 7;                           \
        gload_lds16(aG + kb_ + (size_t)(h) * (128 * K_IN * 2),                 \
                    aL + ((par) << 15) + ((h) << 14));                         \
        gload_lds16(aG + kb_ + (size_t)(h) * (128 * K_IN * 2) + 64 * K_IN * 2, \
                    aL + ((par) << 15) + ((h) << 14) + 8192);                  \
    } while (0)

    // ---- fragment addressing (32x32x16) ----
    const int lane = t & 63;
    const int wave = t >> 6;
    const int wr = wave >> 2;            // 0..1 : M half (128 rows)
    const int wc = wave & 3;             // 0..3 : N quarter (64 cols)
    const int fr = lane & 31;            // row within 32-row frag
    const int kh = lane >> 5;            // k-half (8 of 16 k per slice)
    int cS[4];                           // swizzled 16B-chunk byte offsets
#pragma unroll
    for (int s = 0; s < 4; ++s)
        cS[s] = (((s << 1) | kh) ^ (fr & 7)) << 4;
    const char* aRd = (const char*)As + ((wr << 7) + fr) * 128;

    // B per-lane global base: col = colBase + wc*64 + n*32 + fr, k = kh*8 + ...
    const bf16* bGr = Bt + (size_t)(colBase + (wc << 6) + fr) * K_IN + (kh << 3);

// B K-tile fragment load: 8x 16B per lane. sched_barrier(0) pins issue order
// (nothing may hoist above it -> A-gloads issued earlier stay earlier).
#define LOAD_B(buf, ktN) do {                                                  \
        __builtin_amdgcn_sched_barrier(0);                                     \
        const size_t kb_ = (size_t)((ktN) & 63) << 6;                          \
        _Pragma("unroll")                                                      \
        for (int n = 0; n < 2; ++n)                                            \
            _Pragma("unroll")                                                  \
            for (int s = 0; s < 4; ++s)                                        \
                buf[n][s] = *(const bf16x8*)(bGr + (size_t)n * (32 * K_IN)     \
                                             + kb_ + (s << 4));                \
    } while (0)

// Phase q: 4 A ds_read_b128 (m-frag q), 8 MFMA on register B.
// POST: B-load block; VM: vmcnt(8); BAR: barrier.
#define PHASE(par, q, bufB, STAGE_STMT, POST_STMT, VM, BAR) do {               \
        bf16x8 a_[4];                                                          \
        _Pragma("unroll")                                                      \
        for (int s = 0; s < 4; ++s)                                            \
            a_[s] = *(const bf16x8*)(aRd + ((par) << 15) + ((q) << 12) + cS[s]);\
        STAGE_STMT;                                                            \
        __builtin_amdgcn_s_setprio(1);                                         \
        _Pragma("unroll")                                                      \
        for (int s = 0; s < 4; ++s) {                                          \
            acc[q][0] = MFMA32(a_[s], bufB[0][s], acc[q][0], 0, 0, 0);         \
            acc[q][1] = MFMA32(a_[s], bufB[1][s], acc[q][1], 0, 0, 0);         \
        }                                                                      \
        __builtin_amdgcn_s_setprio(0);                                         \
        POST_STMT;                                                             \
        if (VM) {                                                              \
            asm volatile("s_waitcnt vmcnt(8)" ::: "memory");                   \
            __builtin_amdgcn_sched_barrier(0);                                 \
        }                                                                      \
        if (BAR) {                                                             \
            __builtin_amdgcn_sched_barrier(0);                                 \
            __builtin_amdgcn_s_barrier();                                      \
            __builtin_amdgcn_sched_barrier(0);                                 \
        }                                                                      \
    } while (0)
#define NOPST (void)0

    f32x16 acc[4][2];
#pragma unroll
    for (int m = 0; m < 4; ++m)
#pragma unroll
        for (int n = 0; n < 2; ++n)
#pragma unroll
            for (int e = 0; e < 16; ++e) acc[m][n][e] = 0.f;

    bf16x8 b0[2][4], b1[2][4];   // per-K-tile B buffers (even kt -> b0)

    // prologue: A(0)->par0, A(1)->par1 (8 gloads), then B(0)->b0, B(1)->b1.
    // vmcnt(8) retires A8 + b0 (keeps b1's 8 in flight = steady-state shape).
    STAGE_A(0, 0, 0); STAGE_A(0, 1, 0);
    STAGE_A(1, 0, 1); STAGE_A(1, 1, 1);
    LOAD_B(b0, 0);
    LOAD_B(b1, 1);
    asm volatile("s_waitcnt vmcnt(8)" ::: "memory");
    __builtin_amdgcn_sched_barrier(0);
    __builtin_amdgcn_s_barrier();
    __builtin_amdgcn_sched_barrier(0);

    for (int i = 0; i < 32; ++i) {          // 2 K-tiles per iter, K = 64*64
        const int kA1 = 2 * i + 1;          // A(kt+1) -> par1 (restage noop i=0)
        const int kA0 = 2 * i + 2;          // A(kt+2) -> par0
        const int kB0 = 2 * i + 2;          // B(kt+2) -> b0
        const int kB1 = 2 * i + 3;          // B(kt+3) -> b1
        // phases 1-4: kt=2i from par0 A, b0 B
        PHASE(0, 0, b0, STAGE_A(kA1, 0, 1), NOPST, 0, 0);
        PHASE(0, 1, b0, STAGE_A(kA1, 1, 1), NOPST, 0, 0);
        PHASE(0, 2, b0, NOPST, NOPST, 0, 0);
        PHASE(0, 3, b0, NOPST, LOAD_B(b0, kB0), 1, 1);  // vmcnt(8)+barrier
        // phases 5-8: kt=2i+1 from par1 A, b1 B
        PHASE(1, 0, b1, STAGE_A(kA0, 0, 0), NOPST, 0, 0);
        PHASE(1, 1, b1, STAGE_A(kA0, 1, 0), NOPST, 0, 0);
        PHASE(1, 2, b1, NOPST, NOPST, 0, 0);
        PHASE(1, 3, b1, NOPST, LOAD_B(b1, kB1), 1, 1);  // vmcnt(8)+barrier
    }

    asm volatile("s_waitcnt vmcnt(0)" ::: "memory");  // drain tail junk loads
    // keep final (junk) B loads live so DCE cannot shift the vmcnt counts
    asm volatile("" :: "v"(b0[0][0]), "v"(b0[1][3]), "v"(b1[0][0]), "v"(b1[1][3]));

    // epilogue: 32x32 C/D layout col=lane&31, row=(reg&3)+8*(reg>>2)+4*kh
#pragma unroll
    for (int n = 0; n < 2; ++n) {
        const int c = colBase + (wc << 6) + (n << 5) + fr;
        float b = bias[c];
        if (z) b = softplus_fast(b);
#pragma unroll
        for (int m = 0; m < 4; ++m) {
            const int rb = rowBase + (wr << 7) + (m << 5) + (kh << 2);
#pragma unroll
            for (int reg = 0; reg < 16; ++reg) {
                const int row = rb + (reg & 3) + ((reg >> 2) << 3);
                C[(size_t)row * N_OUT + c] = acc[m][n][reg] + b;
            }
        }
    }
#undef STAGE_A
#undef LOAD_B
#undef PHASE
#undef NOPST
}

// ---------------------------------------------------------------------------
// kl_finish: reduce partials (3 x n) in double, write scalar kl.
// ---------------------------------------------------------------------------
__global__ __launch_bounds__(256) void kl_finish(const float* __restrict__ partials,
                                                 const int n,
                                                 float* __restrict__ out) {
    __shared__ double red[256];
    const int t = threadIdx.x;
    double sums[3];
    for (int v = 0; v < 3; v++) {
        double a = 0.0;
        for (int i = t; i < n; i += 256) a += (double)partials[v * n + i];
        red[t] = a;
        __syncthreads();
        for (int s = 128; s > 0; s >>= 1) {
            if (t < s) red[t] += red[t + s];
            __syncthreads();
        }
        sums[v] = red[0];
        __syncthreads();
    }
    if (t == 0) {
        const double mean_log = sums[0] / 16777216.0;
        const double mean_sp  = sums[1] / 16777216.0;
        const double kl = -0.5 * (4096.0 * mean_log - sums[2] - 4096.0 * mean_sp);
        out[0] = (float)kl;
    }
}

// ---------------------------------------------------------------------------
// Fallback (only if ws too small): naive fp32 dual GEMM + partials.
// ---------------------------------------------------------------------------
__global__ void fb_partials(const float* __restrict__ wmu,
                            const float* __restrict__ wsg,
                            float* __restrict__ partials) {
    __shared__ float red[256];
    const int t = threadIdx.x;
    float s_abs = 0.f, s_sp = 0.f, s_log = 0.f;
    for (int i = blockIdx.x * 256 + t; i < NELEM; i += 1024 * 256) {
        s_abs += fabsf(wmu[i]);
        const float sp = softplus_fast(wsg[i]);
        s_sp += sp;
        s_log += __logf(sp);
    }
    float vals[3] = { s_log, s_sp, s_abs };
    for (int v = 0; v < 3; v++) {
        __syncthreads();
        red[t] = vals[v];
        __syncthreads();
        for (int s = 128; s > 0; s >>= 1) {
            if (t < s) red[t] += red[t + s];
            __syncthreads();
        }
        if (t == 0) partials[v * 1024 + blockIdx.x] = red[0];
    }
}

__global__ void fb_gemm(const float* __restrict__ A,
                        const float* __restrict__ Wm,
                        const float* __restrict__ Ws,
                        const float* __restrict__ bmu,
                        const float* __restrict__ bsg,
                        float* __restrict__ Cmu,
                        float* __restrict__ Csg) {
    __shared__ float As_[16][17], Bm[16][17], Bs_[16][17];
    const int tx = threadIdx.x, ty = threadIdx.y;
    const int row = blockIdx.y * 16 + ty;
    const int col = blockIdx.x * 16 + tx;
    float am = 0.f, as = 0.f;
    for (int k0 = 0; k0 < K_IN; k0 += 16) {
        As_[ty][tx] = A[(size_t)row * K_IN + k0 + tx];
        Bm[ty][tx]  = Wm[(size_t)(k0 + ty) * N_OUT + col];
        Bs_[ty][tx] = softplus_fast(Ws[(size_t)(k0 + ty) * N_OUT + col]);
        __syncthreads();
#pragma unroll
        for (int kk = 0; kk < 16; kk++) {
            const float av = As_[ty][kk];
            am += av * Bm[kk][tx];
            as += av * av * Bs_[kk][tx];
        }
        __syncthreads();
    }
    Cmu[(size_t)row * N_OUT + col] = am + bmu[col];
    Csg[(size_t)row * N_OUT + col] = as + softplus_fast(bsg[col]);
}

// ---------------------------------------------------------------------------
extern "C" void kernel_launch(void* const* d_in, const int* in_sizes, int n_in,
                              void* d_out, int out_size, void* d_ws, size_t ws_size,
                              hipStream_t stream) {
    const float* mu_in   = (const float*)d_in[0];
    // d_in[1] (sigma_in) unused by the reference
    const float* w_mu    = (const float*)d_in[2];
    const float* w_sigma = (const float*)d_in[3];
    const float* b_mu    = (const float*)d_in[4];
    const float* b_sigma = (const float*)d_in[5];

    float* out_mu  = (float*)d_out;
    float* out_sig = out_mu + (size_t)NELEM;
    float* out_kl  = out_mu + 2 * (size_t)NELEM;

    const size_t mat  = (size_t)NELEM;
    const size_t need = mat * 2 * 4 /* 4 bf16 matrices */ + 3 * 4096 * sizeof(float);

    if (ws_size >= need) {
        bf16* A      = (bf16*)d_ws;
        bf16* A2     = A + mat;
        bf16* Wmu_t  = A2 + mat;
        bf16* Wsg_t  = Wmu_t + mat;
        float* parts = (float*)(Wsg_t + mat);

        prep_all<<<2048 + 8192, 256, 0, stream>>>(
            w_mu, w_sigma, Wmu_t, Wsg_t, parts,
            (const float4*)mu_in, (u16x8*)A, (u16x8*)A2);
        gemm_bf16<<<dim3(16, 16, 2), 512, 0, stream>>>(
            A, Wmu_t, b_mu, out_mu, A2, Wsg_t, b_sigma, out_sig);
        kl_finish<<<1, 256, 0, stream>>>(parts, 2048, out_kl);
    } else {
        // emergency fallback: slow but correct fp32 path (needs 12KB ws)
        float* parts = (float*)d_ws;
        fb_partials<<<1024, 256, 0, stream>>>(w_mu, w_sigma, parts);
        fb_gemm<<<dim3(256, 256), dim3(16, 16), 0, stream>>>(
            mu_in, w_mu, w_sigma, b_mu, b_sigma, out_mu, out_sig);
        kl_finish<<<1, 256, 0, stream>>>(parts, 1024, out_kl);
    }
}

// Round 10
// 560.763 us; speedup vs baseline: 1.2822x; 1.1519x over previous
//
#include <hip/hip_runtime.h>
#include <hip/hip_bf16.h>
#include <math.h>

#define M_BATCH   4096
#define K_IN      4096
#define N_OUT     4096
#define NELEM     16777216   // 4096*4096

typedef __bf16 bf16;
typedef bf16  bf16x8 __attribute__((ext_vector_type(8)));
typedef float f32x4  __attribute__((ext_vector_type(4)));
typedef float f32x16 __attribute__((ext_vector_type(16)));
typedef unsigned short u16;
typedef u16 u16x8 __attribute__((ext_vector_type(8)));

// fast softplus: hardware v_exp/v_log, poly for small e (w_sigma in [-12,-2.2])
__device__ __forceinline__ float softplus_fast(float x) {
    if (x > 15.f) return x;
    const float e = __expf(x);
    if (e < 0.0883f)  // log1p(e) = e - e^2/2 + e^3/3, trunc err < 2e-6 rel
        return e * (1.f + e * (-0.5f + e * 0.3333333f));
    return __logf(1.f + e);
}

__device__ __forceinline__ unsigned short f2bf_bits(float x) {
    bf16 b = (bf16)x;
    return __builtin_bit_cast(unsigned short, b);
}

// async global->LDS, 16B per lane. LDS dst must be wave-uniform base + lane*16.
__device__ __forceinline__ void gload_lds16(const void* g, void* l) {
    __builtin_amdgcn_global_load_lds(
        (__attribute__((address_space(1))) void*)g,
        (__attribute__((address_space(3))) void*)l,
        16, 0, 0);
}

// ---------------------------------------------------------------------------
// prep_all v2 (R6, kept unchanged).
// ---------------------------------------------------------------------------
__global__ __launch_bounds__(256) void prep_all(const float* __restrict__ wmu,
                                                const float* __restrict__ wsg,
                                                bf16* __restrict__ Wmu_t,
                                                bf16* __restrict__ Wsg_t,
                                                float* __restrict__ partials,
                                                const float4* __restrict__ mu,
                                                u16x8* __restrict__ A8,
                                                u16x8* __restrict__ A28) {
    __shared__ bf16 tmu[128][65];
    __shared__ bf16 tsg[128][65];
    __shared__ float wred[4][3];

    const int t   = threadIdx.x;
    const int bid = blockIdx.x;

    if (bid >= 2048) {                       // ---- prep_a part ----
        const int i = (bid - 2048) * 256 + t;        // u16x8-granule index
        const float4 v0 = mu[2 * i];
        const float4 v1 = mu[2 * i + 1];
        u16x8 a, a2;
        a[0] = f2bf_bits(v0.x); a[1] = f2bf_bits(v0.y);
        a[2] = f2bf_bits(v0.z); a[3] = f2bf_bits(v0.w);
        a[4] = f2bf_bits(v1.x); a[5] = f2bf_bits(v1.y);
        a[6] = f2bf_bits(v1.z); a[7] = f2bf_bits(v1.w);
        a2[0] = f2bf_bits(v0.x * v0.x); a2[1] = f2bf_bits(v0.y * v0.y);
        a2[2] = f2bf_bits(v0.z * v0.z); a2[3] = f2bf_bits(v0.w * v0.w);
        a2[4] = f2bf_bits(v1.x * v1.x); a2[5] = f2bf_bits(v1.y * v1.y);
        a2[6] = f2bf_bits(v1.z * v1.z); a2[7] = f2bf_bits(v1.w * v1.w);
        A8[i]  = a;
        A28[i] = a2;
        return;
    }

    // ---- prep_w part: 128(i) x 64(o) tile ----
    const int ti = bid >> 6;            // i (K) tile, 0..31  (128 rows each)
    const int tj = bid & 63;            // o (N) tile, 0..63  (64 cols each)
    const int r  = t >> 4;              // 0..15
    const int c4 = (t & 15) << 2;       // 0,4,..,60

    float s_abs = 0.f, s_sp = 0.f, s_log = 0.f;

    for (int rr = 0; rr < 128; rr += 16) {
        const int row = rr + r;
        const size_t goff = (size_t)(ti * 128 + row) * N_OUT + tj * 64 + c4;
        const float4 vm = *(const float4*)(wmu + goff);
        const float4 vs = *(const float4*)(wsg + goff);
        const float sp0 = softplus_fast(vs.x), sp1 = softplus_fast(vs.y);
        const float sp2 = softplus_fast(vs.z), sp3 = softplus_fast(vs.w);
        s_abs += fabsf(vm.x) + fabsf(vm.y) + fabsf(vm.z) + fabsf(vm.w);
        s_sp  += sp0 + sp1 + sp2 + sp3;
        s_log += __logf(sp0) + __logf(sp1) + __logf(sp2) + __logf(sp3);
        tmu[row][c4 + 0] = (bf16)vm.x; tmu[row][c4 + 1] = (bf16)vm.y;
        tmu[row][c4 + 2] = (bf16)vm.z; tmu[row][c4 + 3] = (bf16)vm.w;
        tsg[row][c4 + 0] = (bf16)sp0;  tsg[row][c4 + 1] = (bf16)sp1;
        tsg[row][c4 + 2] = (bf16)sp2;  tsg[row][c4 + 3] = (bf16)sp3;
    }
    __syncthreads();

    // transposed write: Wt[o][i] = tile[i][o]; 16 threads x 16 B = 256 B/row
#pragma unroll
    for (int p = 0; p < 4; ++p) {
        const int jj = p * 16 + (t >> 4);   // o within tile
        const int i0 = (t & 15) << 3;       // i chunk (8 elems)
        u16x8 om, os;
#pragma unroll
        for (int e = 0; e < 8; ++e) {
            om[e] = __builtin_bit_cast(unsigned short, tmu[i0 + e][jj]);
            os[e] = __builtin_bit_cast(unsigned short, tsg[i0 + e][jj]);
        }
        const size_t o = (size_t)(tj * 64 + jj) * K_IN + ti * 128 + i0;
        *(u16x8*)(Wmu_t + o) = om;
        *(u16x8*)(Wsg_t + o) = os;
    }

    // KL partials: shfl_xor wave-reduce, one LDS combine
    float v0 = s_log, v1 = s_sp, v2 = s_abs;
#pragma unroll
    for (int off = 32; off; off >>= 1) {
        v0 += __shfl_xor(v0, off, 64);
        v1 += __shfl_xor(v1, off, 64);
        v2 += __shfl_xor(v2, off, 64);
    }
    if ((t & 63) == 0) {
        wred[t >> 6][0] = v0; wred[t >> 6][1] = v1; wred[t >> 6][2] = v2;
    }
    __syncthreads();
    if (t == 0) {
        partials[0 * 2048 + bid] = wred[0][0] + wred[1][0] + wred[2][0] + wred[3][0];
        partials[1 * 2048 + bid] = wred[0][1] + wred[1][1] + wred[2][1] + wred[3][1];
        partials[2 * 2048 + bid] = wred[0][2] + wred[1][2] + wred[2][2] + wred[3][2];
    }
}

// ---------------------------------------------------------------------------
// gemm_bf16: C[M,N] = A[M,K](bf16) * Bt[N,K]^T(bf16) + bias  (fp32 out)
// R10: REVERT to R6 (best measured: gemm 258us) + k-slice phase
// decomposition. R9 proved B-from-global is L2-scatter-bound (370us) and
// that SQ_LDS_BANK_CONFLICT is proportional to ds_read_b128 count
// (intrinsic ~8cyc/read, 2-lane/bank floor) — not a swizzle artifact.
// Structure: 256x256 tile, BK=64, 8 waves (2M x 4N, 128x64/wave), 128 KiB
// dbuf LDS (A and B both staged, R6 flat [par][256][64], 16B-chunk XOR
// swizzle), 32x32x16 MFMA, R4 4-barrier skeleton, vmcnt(4)@ph4/ph8.
// NEW: phase q = k-slice q (was: m-fragment q). Each phase reads 4 A-frags
// (m0..3) + 2 B-frags (n0,1) at ks=q — 6 evenly-spread ds_reads/phase
// (was 4..12 burst at q0) — and issues 8 MFMAs over 8 DISTINCT acc
// elements (no intra-phase dependent pair). B register lifetime 1 phase
// (was 4): ~24 VGPR pressure drop. Per-acc ks order 0,1,2,3 preserved
// -> bitwise-identical C. XCD 4x8 remap kept (FETCH -33%, R2-confirmed).
// ---------------------------------------------------------------------------
#define MFMA32 __builtin_amdgcn_mfma_f32_32x32x16_bf16

__global__ __launch_bounds__(512, 2) void gemm_bf16(
    const bf16* __restrict__ A1,  const bf16* __restrict__ Bt1,
    const float* __restrict__ bias1, float* __restrict__ C1,
    const bf16* __restrict__ A2_, const bf16* __restrict__ Bt2,
    const float* __restrict__ bias2, float* __restrict__ C2) {

    __shared__ bf16 As[2 * 256 * 64];   // [par][row 256][k 64], 64 KiB
    __shared__ bf16 Bs[2 * 256 * 64];   // 64 KiB

    const int z = blockIdx.z;
    const bf16*  A    = z ? A2_   : A1;
    const bf16*  Bt   = z ? Bt2   : Bt1;
    const float* bias = z ? bias2 : bias1;
    float*       C    = z ? C2    : C1;

    const int t = threadIdx.x;
    // XCD-aware remap: each XCD gets a contiguous 4x8 block of the tile grid.
    const int id   = blockIdx.y * 16 + blockIdx.x;  // 0..255 per z-slice
    const int xcd  = id & 7, cc_ = id >> 3;
    const int rowBase = (((xcd >> 1) << 2) + (cc_ >> 3)) << 8;
    const int colBase = (((xcd & 1) << 3) + (cc_ & 7)) << 8;

    // ---- staging (R6): gload_lds writes linear (t*16); source chunk
    // inverse-swizzled so reads can swizzle (rule 21).
    const int srow   = t >> 3;                  // 0..63 (row within 64-row slab)
    const int schunk = (t & 7) ^ (srow & 7);    // source 16B chunk within row
    const char* aG = (const char*)(A  + (size_t)(rowBase + srow) * K_IN + schunk * 8);
    const char* bG = (const char*)(Bt + (size_t)(colBase + srow) * K_IN + schunk * 8);
    char* aL = (char*)As + t * 16;
    char* bL = (char*)Bs + t * 16;

#define STAGE_A(kt, h, par) do {                                               \
        const size_t kb_ = (size_t)((kt) & 63) << 7;                           \
        gload_lds16(aG + kb_ + (size_t)(h) * (128 * K_IN * 2),                 \
                    aL + ((par) << 15) + ((h) << 14));                         \
        gload_lds16(aG + kb_ + (size_t)(h) * (128 * K_IN * 2) + 64 * K_IN * 2, \
                    aL + ((par) << 15) + ((h) << 14) + 8192);                  \
    } while (0)
#define STAGE_B(kt, h, par) do {                                               \
        const size_t kb_ = (size_t)((kt) & 63) << 7;                           \
        gload_lds16(bG + kb_ + (size_t)(h) * (128 * K_IN * 2),                 \
                    bL + ((par) << 15) + ((h) << 14));                         \
        gload_lds16(bG + kb_ + (size_t)(h) * (128 * K_IN * 2) + 64 * K_IN * 2, \
                    bL + ((par) << 15) + ((h) << 14) + 8192);                  \
    } while (0)

    // ---- fragment read addressing (32x32x16, flat 128B rows) ----
    const int lane = t & 63;
    const int wave = t >> 6;
    const int wr = wave >> 2;            // 0..1 : M half (128 rows)
    const int wc = wave & 3;             // 0..3 : N quarter (64 cols)
    const int fr = lane & 31;            // row within 32-row frag
    const int kh = lane >> 5;            // k-half (8 of 16 k per slice)
    int cS[4];                           // swizzled 16B-chunk byte offsets
#pragma unroll
    for (int s = 0; s < 4; ++s)
        cS[s] = (((s << 1) | kh) ^ (fr & 7)) << 4;
    const char* aRd = (const char*)As + ((wr << 7) + fr) * 128;
    const char* bRd = (const char*)Bs + ((wc << 6) + fr) * 128;

#define DS_A(par, m, ks) (*(const bf16x8*)(aRd + ((par) << 15) + ((m) << 12) + cS[ks]))
#define DS_B(par, n, ks) (*(const bf16x8*)(bRd + ((par) << 15) + ((n) << 12) + cS[ks]))

// Phase q = k-slice q: 4 A-frags (m0..3) + 2 B-frags (n0,1), 8 independent
// MFMAs (8 distinct acc elements). Per-acc ks order 0..3 across phases.
// BAR: 0 = free-run, 1 = barrier after MFMA; VM: vmcnt(4) before barrier.
#define PHASE(par, q, STAGE_STMT, VM, BAR) do {                                \
        bf16x8 bq0 = DS_B(par, 0, q);                                          \
        bf16x8 bq1 = DS_B(par, 1, q);                                          \
        bf16x8 a_[4];                                                          \
        _Pragma("unroll")                                                      \
        for (int m = 0; m < 4; ++m)                                            \
            a_[m] = DS_A(par, m, q);                                           \
        STAGE_STMT;                                                            \
        __builtin_amdgcn_s_setprio(1);                                         \
        _Pragma("unroll")                                                      \
        for (int m = 0; m < 4; ++m) {                                          \
            acc[m][0] = MFMA32(a_[m], bq0, acc[m][0], 0, 0, 0);                \
            acc[m][1] = MFMA32(a_[m], bq1, acc[m][1], 0, 0, 0);                \
        }                                                                      \
        __builtin_amdgcn_s_setprio(0);                                         \
        if (VM) {                                                              \
            asm volatile("s_waitcnt vmcnt(4)" ::: "memory");                   \
            __builtin_amdgcn_sched_barrier(0);                                 \
        }                                                                      \
        if (BAR) {                                                             \
            __builtin_amdgcn_sched_barrier(0);                                 \
            __builtin_amdgcn_s_barrier();                                      \
            __builtin_amdgcn_sched_barrier(0);                                 \
        }                                                                      \
    } while (0)

    f32x16 acc[4][2];
#pragma unroll
    for (int m = 0; m < 4; ++m)
#pragma unroll
        for (int n = 0; n < 2; ++n)
#pragma unroll
            for (int e = 0; e < 16; ++e) acc[m][n][e] = 0.f;

    // prologue: stage kt0 + kt1 fully (16 loads); retire kt0 (keep kt1 in flight)
    STAGE_A(0, 0, 0); STAGE_A(0, 1, 0);
    STAGE_B(0, 0, 0); STAGE_B(0, 1, 0);
    STAGE_A(1, 0, 1); STAGE_A(1, 1, 1);
    STAGE_B(1, 0, 1); STAGE_B(1, 1, 1);
    asm volatile("s_waitcnt vmcnt(8)" ::: "memory");
    __builtin_amdgcn_sched_barrier(0);
    __builtin_amdgcn_s_barrier();
    __builtin_amdgcn_sched_barrier(0);

    for (int i = 0; i < 32; ++i) {          // 2 K-tiles per iter, K = 64*64
        const int kA1 = 2 * i + 1;          // A(kt+1) -> par1 (restage noop i=0)
        const int kB0 = 2 * i + 2;          // B(kt+2) -> par0
        const int kA0 = 2 * i + 2;          // A(kt+2) -> par0
        const int kB1 = 2 * i + 3;          // B(kt+3) -> par1
        // phases 1-4: compute kt=2i from par0
        PHASE(0, 0, STAGE_A(kA1, 0, 1), 0, 0);
        PHASE(0, 1, STAGE_A(kA1, 1, 1), 0, 1);   // end-ph2 barrier
        PHASE(0, 2, STAGE_B(kB0, 0, 0), 0, 0);
        PHASE(0, 3, STAGE_B(kB0, 1, 0), 1, 1);   // vmcnt(4) + end-ph4 barrier
        // phases 5-8: compute kt=2i+1 from par1
        PHASE(1, 0, STAGE_A(kA0, 0, 0), 0, 0);
        PHASE(1, 1, STAGE_A(kA0, 1, 0), 0, 1);   // end-ph6 barrier
        PHASE(1, 2, STAGE_B(kB1, 0, 1), 0, 0);
        PHASE(1, 3, STAGE_B(kB1, 1, 1), 1, 1);   // vmcnt(4) + end-ph8 barrier
    }

    asm volatile("s_waitcnt vmcnt(0)" ::: "memory");  // drain tail junk loads

    // epilogue: 32x32 C/D layout col=lane&31, row=(reg&3)+8*(reg>>2)+4*kh
#pragma unroll
    for (int n = 0; n < 2; ++n) {
        const int c = colBase + (wc << 6) + (n << 5) + fr;
        float b = bias[c];
        if (z) b = softplus_fast(b);
#pragma unroll
        for (int m = 0; m < 4; ++m) {
            const int rb = rowBase + (wr << 7) + (m << 5) + (kh << 2);
#pragma unroll
            for (int reg = 0; reg < 16; ++reg) {
                const int row = rb + (reg & 3) + ((reg >> 2) << 3);
                C[(size_t)row * N_OUT + c] = acc[m][n][reg] + b;
            }
        }
    }
#undef STAGE_A
#undef STAGE_B
#undef DS_A
#undef DS_B
#undef PHASE
}

// ---------------------------------------------------------------------------
// kl_finish: reduce partials (3 x n) in double, write scalar kl.
// ---------------------------------------------------------------------------
__global__ __launch_bounds__(256) void kl_finish(const float* __restrict__ partials,
                                                 const int n,
                                                 float* __restrict__ out) {
    __shared__ double red[256];
    const int t = threadIdx.x;
    double sums[3];
    for (int v = 0; v < 3; v++) {
        double a = 0.0;
        for (int i = t; i < n; i += 256) a += (double)partials[v * n + i];
        red[t] = a;
        __syncthreads();
        for (int s = 128; s > 0; s >>= 1) {
            if (t < s) red[t] += red[t + s];
            __syncthreads();
        }
        sums[v] = red[0];
        __syncthreads();
    }
    if (t == 0) {
        const double mean_log = sums[0] / 16777216.0;
        const double mean_sp  = sums[1] / 16777216.0;
        const double kl = -0.5 * (4096.0 * mean_log - sums[2] - 4096.0 * mean_sp);
        out[0] = (float)kl;
    }
}

// ---------------------------------------------------------------------------
// Fallback (only if ws too small): naive fp32 dual GEMM + partials.
// ---------------------------------------------------------------------------
__global__ void fb_partials(const float* __restrict__ wmu,
                            const float* __restrict__ wsg,
                            float* __restrict__ partials) {
    __shared__ float red[256];
    const int t = threadIdx.x;
    float s_abs = 0.f, s_sp = 0.f, s_log = 0.f;
    for (int i = blockIdx.x * 256 + t; i < NELEM; i += 1024 * 256) {
        s_abs += fabsf(wmu[i]);
        const float sp = softplus_fast(wsg[i]);
        s_sp += sp;
        s_log += __logf(sp);
    }
    float vals[3] = { s_log, s_sp, s_abs };
    for (int v = 0; v < 3; v++) {
        __syncthreads();
        red[t] = vals[v];
        __syncthreads();
        for (int s = 128; s > 0; s >>= 1) {
            if (t < s) red[t] += red[t + s];
            __syncthreads();
        }
        if (t == 0) partials[v * 1024 + blockIdx.x] = red[0];
    }
}

__global__ void fb_gemm(const float* __restrict__ A,
                        const float* __restrict__ Wm,
                        const float* __restrict__ Ws,
                        const float* __restrict__ bmu,
                        const float* __restrict__ bsg,
                        float* __restrict__ Cmu,
                        float* __restrict__ Csg) {
    __shared__ float As_[16][17], Bm[16][17], Bs_[16][17];
    const int tx = threadIdx.x, ty = threadIdx.y;
    const int row = blockIdx.y * 16 + ty;
    const int col = blockIdx.x * 16 + tx;
    float am = 0.f, as = 0.f;
    for (int k0 = 0; k0 < K_IN; k0 += 16) {
        As_[ty][tx] = A[(size_t)row * K_IN + k0 + tx];
        Bm[ty][tx]  = Wm[(size_t)(k0 + ty) * N_OUT + col];
        Bs_[ty][tx] = softplus_fast(Ws[(size_t)(k0 + ty) * N_OUT + col]);
        __syncthreads();
#pragma unroll
        for (int kk = 0; kk < 16; kk++) {
            const float av = As_[ty][kk];
            am += av * Bm[kk][tx];
            as += av * av * Bs_[kk][tx];
        }
        __syncthreads();
    }
    Cmu[(size_t)row * N_OUT + col] = am + bmu[col];
    Csg[(size_t)row * N_OUT + col] = as + softplus_fast(bsg[col]);
}

// ---------------------------------------------------------------------------
extern "C" void kernel_launch(void* const* d_in, const int* in_sizes, int n_in,
                              void* d_out, int out_size, void* d_ws, size_t ws_size,
                              hipStream_t stream) {
    const float* mu_in   = (const float*)d_in[0];
    // d_in[1] (sigma_in) unused by the reference
    const float* w_mu    = (const float*)d_in[2];
    const float* w_sigma = (const float*)d_in[3];
    const float* b_mu    = (const float*)d_in[4];
    const float* b_sigma = (const float*)d_in[5];

    float* out_mu  = (float*)d_out;
    float* out_sig = out_mu + (size_t)NELEM;
    float* out_kl  = out_mu + 2 * (size_t)NELEM;

    const size_t mat  = (size_t)NELEM;
    const size_t need = mat * 2 * 4 /* 4 bf16 matrices */ + 3 * 4096 * sizeof(float);

    if (ws_size >= need) {
        bf16* A      = (bf16*)d_ws;
        bf16* A2     = A + mat;
        bf16* Wmu_t  = A2 + mat;
        bf16* Wsg_t  = Wmu_t + mat;
        float* parts = (float*)(Wsg_t + mat);

        prep_all<<<2048 + 8192, 256, 0, stream>>>(
            w_mu, w_sigma, Wmu_t, Wsg_t, parts,
            (const float4*)mu_in, (u16x8*)A, (u16x8*)A2);
        gemm_bf16<<<dim3(16, 16, 2), 512, 0, stream>>>(
            A, Wmu_t, b_mu, out_mu, A2, Wsg_t, b_sigma, out_sig);
        kl_finish<<<1, 256, 0, stream>>>(parts, 2048, out_kl);
    } else {
        // emergency fallback: slow but correct fp32 path (needs 12KB ws)
        float* parts = (float*)d_ws;
        fb_partials<<<1024, 256, 0, stream>>>(w_mu, w_sigma, parts);
        fb_gemm<<<dim3(256, 256), dim3(16, 16), 0, stream>>>(
            mu_in, w_mu, w_sigma, b_mu, b_sigma, out_mu, out_sig);
        kl_finish<<<1, 256, 0, stream>>>(parts, 1024, out_kl);
    }
}